// Round 8
// baseline (404.699 us; speedup 1.0000x reference)
//
#include <hip/hip_runtime.h>

// VectorQuantiser forward, MI355X fp32.
// N=65536 tokens (16x64x64, channel dim 64 strided by 4096), K=1024 codes, D=64.
//
// Round 10: same MFMA+shortlist+exact-rescore architecture (passed twice,
// bit-identical outputs). Round-9 counters: k_mfma 131us, MfmaUtil 7.8%,
// VGPR=36 -> zero prefetch depth, 6-deep dependent MFMA chain, full VMEM
// latency exposed per chunk, each wave re-reading the whole 256KB codebook
// from L2. Fixes:
//  - k_mfma: e double-buffered in LDS per 64-code group (8x less e traffic),
//    async-split staging (issue loads -> compute -> LDS write -> barrier),
//    pad stride 36 u32 (conflict-free ds_read_b128), acc split into 3
//    independent 2-deep chains (hh/hl/lh summed; accs ~1e-3 so the extra
//    roundings are ~1e-10 -- margin headroom unchanged), launch_bounds(512,2).
//    colmax -> LDS u32 atomicMax on f32_ord (monotone bijection, float
//    recovered bit-exactly).
//  - k_rowrescore: wave-per-candidate, lanes=codes. n is wave-uniform so the
//    scrambled list order no longer scatters z loads; e rows staged in LDS.
//    Per-code dot is the verbatim 4-chain fmaf; wave max of packed keys ==
//    sequential strict-> scan (ties via ~k).
// All rounding-sensitive exact paths verbatim from the passing code.

#define MARGIN 2e-4f

// ---- ws layout (bytes) ----
#define WS_ROW   0         // u64 wsrow[65536]
#define WS_COL   524288    // u64 wscol[1024]
#define WS_CNT   532480    // u32 counts[1024]
#define WS_LOSS  536576    // double loss_acc
#define WS_EN2   536592    // float en2[1024]
#define WS_LCNT  540688    // u32 lcnt[8]
#define WS_ZN2   541696    // float zn2[65536]            (256KB)
#define WS_EBH   803840    // u16 ebf_hi[1024*64]         (128KB)
#define WS_EBL   934912    // u16 ebf_lo[1024*64]         (128KB)
#define WS_RBM   1065984   // f32 rowbm[65536][8]         (2MB)
#define WS_CBM   3163136   // f32 colbm[1024][512]        (2MB)
#define WS_BYTES 5260288
#define WS_ZERO  540720    // memset range: row/col/cnt/loss/lcnt

typedef __attribute__((ext_vector_type(8))) short short8v;
typedef __attribute__((ext_vector_type(4))) float f32x4;

__device__ __forceinline__ unsigned int f32_ord(float x) {
    unsigned int b = __float_as_uint(x);
    return (b & 0x80000000u) ? ~b : (b | 0x80000000u);
}
__device__ __forceinline__ float ord_f32(unsigned int u) {  // exact inverse
    unsigned int b = (u & 0x80000000u) ? (u & 0x7FFFFFFFu) : ~u;
    return __uint_as_float(b);
}

__device__ __forceinline__ unsigned short f2bf(float f) {  // RNE fp32->bf16
    unsigned int u = __float_as_uint(f);
    return (unsigned short)((u + 0x7FFFu + ((u >> 16) & 1u)) >> 16);
}
__device__ __forceinline__ float bf2f(unsigned short h) {
    return __uint_as_float((unsigned int)h << 16);
}

// numpy pairwise sum of squares over 64 values (verbatim from passing code).
template <typename F>
__device__ __forceinline__ float np_pairwise64_sq(F get) {
    float r[8];
#pragma unroll
    for (int j = 0; j < 8; ++j) {
        float v = get(j);
        r[j] = __fmul_rn(v, v);
    }
#pragma unroll
    for (int i = 8; i < 64; i += 8) {
#pragma unroll
        for (int j = 0; j < 8; ++j) {
            float v = get(i + j);
            r[j] = __fadd_rn(r[j], __fmul_rn(v, v));
        }
    }
    return __fadd_rn(__fadd_rn(__fadd_rn(r[0], r[1]), __fadd_rn(r[2], r[3])),
                     __fadd_rn(__fadd_rn(r[4], r[5]), __fadd_rn(r[6], r[7])));
}

// ---- K0: norms + bf16 hi/lo splits (unchanged from round 9) ----
__global__ __launch_bounds__(256) void k_prep(
    const float* __restrict__ z, const float* __restrict__ emb,
    float* __restrict__ en2, float* __restrict__ zn2,
    unsigned int* __restrict__ zbh32, unsigned int* __restrict__ zbl32,
    unsigned int* __restrict__ ebh32, unsigned int* __restrict__ ebl32) {
    const int t = threadIdx.x;
    if (blockIdx.x < 1024) {
        const int n0  = blockIdx.x * 64;
        const int b   = n0 >> 12;
        const int hw0 = n0 & 4095;

        __shared__ float        zl[64][65];   // [ch][tok], pad 65
        __shared__ unsigned int oh[64][33];   // [tok][wd], pad 33
        __shared__ unsigned int ol[64][33];

#pragma unroll
        for (int it = 0; it < 16; ++it) {
            int idx = it * 256 + t;
            int c = idx >> 6, tok = idx & 63;
            zl[c][tok] = z[(size_t)b * 262144 + (size_t)c * 4096 + hw0 + tok];
        }
        __syncthreads();

        const int tk = t & 63, q = t >> 6;
        if (q == 0)
            zn2[n0 + tk] = np_pairwise64_sq([&](int i) { return zl[i][tk]; });

#pragma unroll
        for (int w8 = 0; w8 < 8; ++w8) {
            int wd = q * 8 + w8;
            float z0 = zl[2 * wd][tk], z1 = zl[2 * wd + 1][tk];
            unsigned short h0 = f2bf(z0), h1 = f2bf(z1);
            oh[tk][wd] = (unsigned int)h0 | ((unsigned int)h1 << 16);
            unsigned short l0 = f2bf(__fsub_rn(z0, bf2f(h0)));
            unsigned short l1 = f2bf(__fsub_rn(z1, bf2f(h1)));
            ol[tk][wd] = (unsigned int)l0 | ((unsigned int)l1 << 16);
        }
        __syncthreads();

#pragma unroll
        for (int it = 0; it < 8; ++it) {
            int idx = it * 256 + t;
            int tok = idx >> 5, wd = idx & 31;
            zbh32[(size_t)(n0 + tok) * 32 + wd] = oh[tok][wd];
            zbl32[(size_t)(n0 + tok) * 32 + wd] = ol[tok][wd];
        }
    } else {
        const int k = (blockIdx.x - 1024) * 256 + t;
        const float* a = emb + (size_t)k * 64;
        float ar[64];
#pragma unroll
        for (int i = 0; i < 64; ++i) ar[i] = a[i];
        en2[k] = np_pairwise64_sq([&](int i) { return ar[i]; });
#pragma unroll
        for (int wd = 0; wd < 32; ++wd) {
            float e0 = ar[2 * wd], e1 = ar[2 * wd + 1];
            unsigned short h0 = f2bf(e0), h1 = f2bf(e1);
            ebh32[k * 32 + wd] = (unsigned int)h0 | ((unsigned int)h1 << 16);
            unsigned short l0 = f2bf(__fsub_rn(e0, bf2f(h0)));
            unsigned short l1 = f2bf(__fsub_rn(e1, bf2f(h1)));
            ebl32[k * 32 + wd] = (unsigned int)l0 | ((unsigned int)l1 << 16);
        }
    }
}

// ---- K1: approximate scores via bf16 MFMA, e LDS-staged + dbuf ----
// grid 512 x 512 (8 waves). Wave w: tokens tw..tw+15, all 1024 codes in 16
// groups of 64 (4 sub-chunks of 16). 3 independent 2-deep MFMA chains.
__global__ __launch_bounds__(512, 2) void k_mfma(
    const unsigned short* __restrict__ zbh, const unsigned short* __restrict__ zbl,
    const unsigned short* __restrict__ ebh, const unsigned short* __restrict__ ebl,
    const float* __restrict__ zn2, const float* __restrict__ en2,
    float* __restrict__ rbm, float* __restrict__ cbm) {
    const int t = threadIdx.x, l = t & 63, w = t >> 6;
    const int n0 = blockIdx.x * 128;
    const int tw = n0 + w * 16;
    const int lm = l & 15, kg = l >> 4;

    // padded e tiles: 64 codes x 36 u32 (32 data + 4 pad) per half, dbuf.
    // quad-bank index of a b-frag read = (9*cl + kg) mod 8 -> any 8
    // consecutive lanes hit 8 distinct bank-quads (conflict-free).
    __shared__ __align__(16) unsigned int eh[2][64 * 36];
    __shared__ __align__(16) unsigned int el[2][64 * 36];
    __shared__ float        en2l[1024];
    __shared__ unsigned int cmU[1024];    // column max as f32_ord (atomicMax)

    for (int i = t; i < 1024; i += 512) { en2l[i] = en2[i]; cmU[i] = 0u; }

    const uint4* EH4 = reinterpret_cast<const uint4*>(ebh);
    const uint4* EL4 = reinterpret_cast<const uint4*>(ebl);
    const int scode = t >> 3, swd = (t & 7) * 4;

    {   // stage group 0
        uint4 hv = EH4[t], lv = EL4[t];
        *reinterpret_cast<uint4*>(&eh[0][scode * 36 + swd]) = hv;
        *reinterpret_cast<uint4*>(&el[0][scode * 36 + swd]) = lv;
    }

    const int tok = tw + lm;
    const short8v ah0 = *reinterpret_cast<const short8v*>(zbh + tok * 64 + kg * 8);
    const short8v ah1 = *reinterpret_cast<const short8v*>(zbh + tok * 64 + 32 + kg * 8);
    const short8v al0 = *reinterpret_cast<const short8v*>(zbl + tok * 64 + kg * 8);
    const short8v al1 = *reinterpret_cast<const short8v*>(zbl + tok * 64 + 32 + kg * 8);

    float nzn2[4];
    {
        const float4 zv = *reinterpret_cast<const float4*>(zn2 + tw + kg * 4);
        nzn2[0] = -zv.x; nzn2[1] = -zv.y; nzn2[2] = -zv.z; nzn2[3] = -zv.w;
    }
    float rmax[4] = {-3.4e38f, -3.4e38f, -3.4e38f, -3.4e38f};

    __syncthreads();

    for (int g = 0; g < 16; ++g) {
        const int buf = g & 1;
        const bool pf = (g < 15);
        uint4 hv, lv;
        if (pf) {   // issue next group's loads early; write AFTER compute
            hv = EH4[(g + 1) * 512 + t];
            lv = EL4[(g + 1) * 512 + t];
        }

#pragma unroll
        for (int sc = 0; sc < 4; ++sc) {
            const int cl = sc * 16 + lm;
            const short8v bh0 = *reinterpret_cast<const short8v*>(&eh[buf][cl * 36 + kg * 4]);
            const short8v bh1 = *reinterpret_cast<const short8v*>(&eh[buf][cl * 36 + 16 + kg * 4]);
            const short8v bl0 = *reinterpret_cast<const short8v*>(&el[buf][cl * 36 + kg * 4]);
            const short8v bl1 = *reinterpret_cast<const short8v*>(&el[buf][cl * 36 + 16 + kg * 4]);

            f32x4 ahh = {0.f, 0.f, 0.f, 0.f};
            f32x4 ahl = {0.f, 0.f, 0.f, 0.f};
            f32x4 alh = {0.f, 0.f, 0.f, 0.f};
            ahh = __builtin_amdgcn_mfma_f32_16x16x32_bf16(ah0, bh0, ahh, 0, 0, 0);
            ahh = __builtin_amdgcn_mfma_f32_16x16x32_bf16(ah1, bh1, ahh, 0, 0, 0);
            ahl = __builtin_amdgcn_mfma_f32_16x16x32_bf16(ah0, bl0, ahl, 0, 0, 0);
            ahl = __builtin_amdgcn_mfma_f32_16x16x32_bf16(ah1, bl1, ahl, 0, 0, 0);
            alh = __builtin_amdgcn_mfma_f32_16x16x32_bf16(al0, bh0, alh, 0, 0, 0);
            alh = __builtin_amdgcn_mfma_f32_16x16x32_bf16(al1, bh1, alh, 0, 0, 0);

            const int code = g * 64 + cl;
            const float en2v = en2l[code];
            float cm = -3.4e38f;
#pragma unroll
            for (int j = 0; j < 4; ++j) {
                float acc = __fadd_rn(__fadd_rn(ahh[j], ahl[j]), alh[j]);
                float s = __fadd_rn(__fsub_rn(nzn2[j], en2v), 2.0f * acc);
                rmax[j] = fmaxf(rmax[j], s);
                cm = fmaxf(cm, s);
            }
            cm = fmaxf(cm, __shfl_xor(cm, 16, 64));
            cm = fmaxf(cm, __shfl_xor(cm, 32, 64));
            if (l < 16) atomicMax(&cmU[code], f32_ord(cm));

            const int c = g * 4 + sc;
            if ((c & 7) == 7) {   // flush a 128-code block of row maxes
#pragma unroll
                for (int j = 0; j < 4; ++j) {
                    float r = rmax[j];
                    r = fmaxf(r, __shfl_xor(r, 1, 64));
                    r = fmaxf(r, __shfl_xor(r, 2, 64));
                    r = fmaxf(r, __shfl_xor(r, 4, 64));
                    r = fmaxf(r, __shfl_xor(r, 8, 64));
                    if (lm == 0)
                        rbm[(size_t)(tw + kg * 4 + j) * 8 + (c >> 3)] = r;
                    rmax[j] = -3.4e38f;
                }
            }
        }

        if (pf) {
            *reinterpret_cast<uint4*>(&eh[buf ^ 1][scode * 36 + swd]) = hv;
            *reinterpret_cast<uint4*>(&el[buf ^ 1][scode * 36 + swd]) = lv;
        }
        __syncthreads();
    }

    for (int code = t; code < 1024; code += 512)
        cbm[(size_t)code * 512 + blockIdx.x] = ord_f32(cmU[code]);
}

// ---- K2: per-token candidate lists from row block-maxes (unchanged) ----
__global__ __launch_bounds__(256) void k_rowmax(
    const float* __restrict__ rbm, unsigned int* __restrict__ lcnt,
    unsigned int* __restrict__ lists) {
    const int n = blockIdx.x * 256 + threadIdx.x;
    const float* bm = rbm + (size_t)n * 8;
    float v[8];
    float g = -3.4e38f;
#pragma unroll
    for (int i = 0; i < 8; ++i) { v[i] = bm[i]; g = fmaxf(g, v[i]); }
    const float thr = g - MARGIN;
#pragma unroll
    for (int cb = 0; cb < 8; ++cb) {
        if (v[cb] >= thr) {
            unsigned int pos = atomicAdd(&lcnt[cb], 1u);
            lists[cb * 65536 + pos] = (unsigned int)n;
        }
    }
}

// ---- K3: exact row rescore — wave-per-candidate, lanes = codes ----
// n is wave-uniform (z loads broadcast; list order irrelevant). e rows in
// LDS (pad 68 -> (kl+j) mod 8 distinct over consecutive lanes). Per-code dot
// is the verbatim 4-chain fmaf; wave max of packed keys == sequential scan.
#define RR_WAVES 4
__global__ __launch_bounds__(256) void k_rowrescore(
    const float* __restrict__ z, const float* __restrict__ emb,
    const float* __restrict__ zn2, const float* __restrict__ en2,
    const unsigned int* __restrict__ lists, const unsigned int* __restrict__ lcnt,
    unsigned long long* __restrict__ wsrow) {
    const int cb = blockIdx.x;
    const int t = threadIdx.x, l = t & 63, w = t >> 6;

    __shared__ __align__(16) float elds[128 * 68];
    for (int i = t; i < 128 * 64; i += 256) {
        int row = i >> 6, col = i & 63;
        elds[row * 68 + col] = emb[(size_t)(cb * 128 + row) * 64 + col];
    }
    __syncthreads();

    const unsigned int cnt = lcnt[cb];
    const unsigned int* list = lists + cb * 65536;
    const float en2a = en2[cb * 128 + l];
    const float en2b = en2[cb * 128 + 64 + l];

    for (unsigned int i = blockIdx.y * RR_WAVES + w; i < cnt;
         i += 64 * RR_WAVES) {
        const int n = (int)list[i];                 // wave-uniform
        const int b = n >> 12, hw = n & 4095;
        const float* zp = z + (size_t)b * 262144 + hw;
        const float nz = -zn2[n];

        unsigned long long best = 0ull;
#pragma unroll
        for (int half = 0; half < 2; ++half) {
            const int kl = half * 64 + l;
            const float* ek = &elds[kl * 68];
            const float en2v = half ? en2b : en2a;
            float c0 = 0.f, c1 = 0.f, c2 = 0.f, c3 = 0.f;
#pragma unroll
            for (int j = 0; j < 16; ++j) {
                const float4 e = *reinterpret_cast<const float4*>(ek + j * 4);
                c0 = fmaf(e.x, zp[(size_t)(4 * j + 0) * 4096], c0);
                c1 = fmaf(e.y, zp[(size_t)(4 * j + 1) * 4096], c1);
                c2 = fmaf(e.z, zp[(size_t)(4 * j + 2) * 4096], c2);
                c3 = fmaf(e.w, zp[(size_t)(4 * j + 3) * 4096], c3);
            }
            float dot = (c0 + c1) + (c2 + c3);
            float d = __fadd_rn(__fsub_rn(nz, en2v), 2.0f * dot);
            unsigned long long key =
                ((unsigned long long)f32_ord(d) << 32) |
                (unsigned long long)(unsigned int)(~(unsigned int)(cb * 128 + kl));
            if (key > best) best = key;
        }
#pragma unroll
        for (int m = 1; m < 64; m <<= 1) {
            unsigned long long o = __shfl_xor(best, m, 64);
            if (o > best) best = o;   // ties: larger key = smaller k
        }
        if (l == 0) atomicMax(&wsrow[n], best);
    }
}

// ---- K4: exact column rescore over candidate token-groups (unchanged) ----
__global__ __launch_bounds__(256) void k_colrescore(
    const float* __restrict__ z, const float* __restrict__ emb,
    const float* __restrict__ zn2, const float* __restrict__ en2,
    const float* __restrict__ cbm, unsigned long long* __restrict__ wscol) {
    const int k = blockIdx.x, t = threadIdx.x;
    __shared__ float red[256];
    __shared__ int   hlist[512];
    __shared__ int   hcnt;
    float a  = cbm[(size_t)k * 512 + t];
    float b2 = cbm[(size_t)k * 512 + 256 + t];
    red[t] = fmaxf(a, b2);
    if (t == 0) hcnt = 0;
    __syncthreads();
    for (int st = 128; st; st >>= 1) {
        if (t < st) red[t] = fmaxf(red[t], red[t + st]);
        __syncthreads();
    }
    const float thr = red[0] - MARGIN;
    if (a >= thr)  { int p = atomicAdd(&hcnt, 1); hlist[p] = t; }
    if (b2 >= thr) { int p = atomicAdd(&hcnt, 1); hlist[p] = t + 256; }
    __syncthreads();
    const int hc = hcnt;
    const float en2k = en2[k];
    const float4* ek = reinterpret_cast<const float4*>(emb + (size_t)k * 64);

    for (int h = 0; h < hc; ++h) {
        const int g = hlist[h];
        if (t < 128) {
            const int n = g * 128 + t;
            const int b = n >> 12, hw = n & 4095;
            const float* zp = z + (size_t)b * 262144 + hw;
            float c0 = 0.f, c1 = 0.f, c2 = 0.f, c3 = 0.f;
#pragma unroll
            for (int j = 0; j < 16; ++j) {
                float4 e = ek[j];
                c0 = fmaf(e.x, zp[(size_t)(4 * j + 0) * 4096], c0);
                c1 = fmaf(e.y, zp[(size_t)(4 * j + 1) * 4096], c1);
                c2 = fmaf(e.z, zp[(size_t)(4 * j + 2) * 4096], c2);
                c3 = fmaf(e.w, zp[(size_t)(4 * j + 3) * 4096], c3);
            }
            float dot = (c0 + c1) + (c2 + c3);
            float d = __fadd_rn(__fsub_rn(-zn2[n], en2k), 2.0f * dot);
            unsigned long long key =
                ((unsigned long long)f32_ord(d) << 32) |
                (unsigned long long)(unsigned int)(~(unsigned int)n);
#pragma unroll
            for (int m = 1; m < 64; m <<= 1) {
                unsigned long long o = __shfl_xor(key, m, 64);
                if (o > key) key = o;    // ties: larger key = smaller n
            }
            if ((t & 63) == 0) atomicMax(&wscol[k], key);
        }
    }
}

// ---- K5: per-token outputs: z_q, indices, hist, loss (unchanged) ----
__global__ __launch_bounds__(256) void k_tokens(
    const float* __restrict__ z, const float* __restrict__ emb,
    const unsigned long long* __restrict__ wsrow,
    unsigned int* __restrict__ counts, double* __restrict__ loss_acc,
    float* __restrict__ out_zq, float* __restrict__ out_idx) {
    const int n  = blockIdx.x * 256 + threadIdx.x;
    const int b  = n >> 12;
    const int hw = n & 4095;

    unsigned long long key = wsrow[n];
    int idx = (int)(~(unsigned int)(key & 0xFFFFFFFFull));
    out_idx[n] = (float)idx;
    atomicAdd(&counts[idx], 1u);

    const float* zp = z + (size_t)b * 262144 + hw;
    float*       op = out_zq + (size_t)b * 262144 + hw;
    const float* ep = emb + (size_t)idx * 64;

    double ls = 0.0;
#pragma unroll
    for (int c = 0; c < 64; ++c) {
        float zc   = zp[(size_t)c * 4096];
        float eq   = ep[c];
        float diff = __fsub_rn(eq, zc);              // fl(z_q - zc)
        float sq   = __fmul_rn(diff, diff);
        ls += (double)sq;
        op[(size_t)c * 4096] = __fadd_rn(zc, diff);  // zc + fl(z_q - zc)
    }

    __shared__ double sred[256];
    sred[threadIdx.x] = ls;
    __syncthreads();
    for (int st = 128; st; st >>= 1) {
        if (threadIdx.x < st) sred[threadIdx.x] += sred[threadIdx.x + st];
        __syncthreads();
    }
    if (threadIdx.x == 0) atomicAdd(loss_acc, sred[0]);
}

// ---- K6: tail — new embedding + scalars (unchanged) ----
__global__ __launch_bounds__(1024) void k_tail(
    const float* __restrict__ z, const float* __restrict__ emb,
    const float* __restrict__ embed_prob,
    const unsigned long long* __restrict__ wscol,
    const unsigned int* __restrict__ counts,
    const double* __restrict__ loss_acc,
    float* __restrict__ out_newemb, float* __restrict__ out_loss,
    float* __restrict__ out_perp, float* __restrict__ out_prob) {
    const int k = blockIdx.x * 16 + (threadIdx.x >> 6);
    const int c = threadIdx.x & 63;

    float avg  = (float)counts[k] * (1.0f / 65536.0f);
    float pnew = __fadd_rn(__fmul_rn(embed_prob[k], 0.99f),
                           __fmul_rn(0.01f, avg));
    float tt = __fdiv_rn(__fmul_rn(__fmul_rn(pnew, 1024.0f), 10.0f), 0.01f);
    float dk = expf(__fsub_rn(-tt, 1e-3f));
    float omd = __fsub_rn(1.0f, dk);

    unsigned long long ck = wscol[k];
    int cn  = (int)(~(unsigned int)(ck & 0xFFFFFFFFull));
    int cb  = cn >> 12;
    int chw = cn & 4095;

    float rf = z[(size_t)cb * 262144 + (size_t)c * 4096 + chw];
    float e  = emb[(size_t)k * 64 + c];
    out_newemb[(size_t)k * 64 + c] =
        __fadd_rn(__fmul_rn(e, omd), __fmul_rn(rf, dk));

    if (blockIdx.x == 0) {
        const int q = threadIdx.x;

        float avg2  = (float)counts[q] * (1.0f / 65536.0f);
        float pnew2 = __fadd_rn(__fmul_rn(embed_prob[q], 0.99f),
                                __fmul_rn(0.01f, avg2));
        out_prob[q] = pnew2;

        float term = __fmul_rn(avg2, logf(__fadd_rn(avg2, 1e-10f)));
        __shared__ double red[1024];
        red[q] = (double)term;
        __syncthreads();
        for (int st = 512; st; st >>= 1) {
            if (q < st) red[q] += red[q + st];
            __syncthreads();
        }
        if (q == 0) {
            float s32 = (float)red[0];
            out_perp[0] = expf(-s32);
            double lm = loss_acc[0] / 4194304.0;
            float  m  = (float)lm;
            out_loss[0] = __fadd_rn(__fmul_rn(0.25f, m), m);  // BETA*m + m
        }
    }
}

extern "C" void kernel_launch(void* const* d_in, const int* in_sizes, int n_in,
                              void* d_out, int out_size, void* d_ws, size_t ws_size,
                              hipStream_t stream) {
    const float* z    = (const float*)d_in[0];   // 16*64*64*64
    const float* emb  = (const float*)d_in[1];   // 1024*64
    const float* prob = (const float*)d_in[2];   // 1024

    float* out        = (float*)d_out;
    float* out_zq     = out;                 // 4194304 floats (16.777 MB)
    float* out_loss   = out + 4194304;
    float* out_perp   = out + 4194305;
    float* out_newemb = out + 4194306;
    float* out_prob   = out + 4259842;
    float* out_idx    = out + 4260866;

    char* ws = (char*)d_ws;
    unsigned long long* wsrow = (unsigned long long*)(ws + WS_ROW);
    unsigned long long* wscol = (unsigned long long*)(ws + WS_COL);
    unsigned int*       cnts  = (unsigned int*)(ws + WS_CNT);
    double*             lacc  = (double*)(ws + WS_LOSS);
    float*              en2   = (float*)(ws + WS_EN2);
    unsigned int*       lcnt  = (unsigned int*)(ws + WS_LCNT);
    float*              zn2   = (float*)(ws + WS_ZN2);
    unsigned short*     ebh   = (unsigned short*)(ws + WS_EBH);
    unsigned short*     ebl   = (unsigned short*)(ws + WS_EBL);
    float*              rbm   = (float*)(ws + WS_RBM);
    float*              cbm   = (float*)(ws + WS_CBM);

    // out_zq doubles as scratch before k_tokens rewrites it:
    //   zbf_hi u16[4.2M] @ bytes [0, 8388608)
    //   zbf_lo u16[4.2M] @ bytes [8388608, 16777216)
    //   lists  u32[8][65536] @ bytes [0, 2097152)   (after k_mfma is done)
    unsigned short* zbh  = (unsigned short*)out_zq;
    unsigned short* zbl  = (unsigned short*)((char*)out_zq + 8388608);
    unsigned int*  lists = (unsigned int*)out_zq;

    hipMemsetAsync(d_ws, 0, WS_ZERO, stream);

    hipLaunchKernelGGL(k_prep, dim3(1028), dim3(256), 0, stream,
                       z, emb, en2, zn2,
                       (unsigned int*)zbh, (unsigned int*)zbl,
                       (unsigned int*)ebh, (unsigned int*)ebl);
    hipLaunchKernelGGL(k_mfma, dim3(512), dim3(512), 0, stream,
                       zbh, zbl, ebh, ebl, zn2, en2, rbm, cbm);
    hipLaunchKernelGGL(k_rowmax, dim3(256), dim3(256), 0, stream,
                       rbm, lcnt, lists);
    hipLaunchKernelGGL(k_colrescore, dim3(1024), dim3(256), 0, stream,
                       z, emb, zn2, en2, cbm, wscol);
    hipLaunchKernelGGL(k_rowrescore, dim3(8, 64), dim3(256), 0, stream,
                       z, emb, zn2, en2, lists, lcnt, wsrow);
    hipLaunchKernelGGL(k_tokens, dim3(256), dim3(256), 0, stream,
                       z, emb, wsrow, cnts, lacc, out_zq, out_idx);
    hipLaunchKernelGGL(k_tail, dim3(64), dim3(1024), 0, stream,
                       z, emb, prob, wscol, cnts, lacc,
                       out_newemb, out_loss, out_perp, out_prob);
}

// Round 9
// 278.932 us; speedup vs baseline: 1.4509x; 1.4509x over previous
//
#include <hip/hip_runtime.h>

// VectorQuantiser forward, MI355X fp32.
// N=65536 tokens (16x64x64, channel dim 64 strided by 4096), K=1024 codes, D=64.
//
// Round 11: per-token CERTIFICATION inside k_mfma. Insight: downstream only
// consumes the argmax INDEX (wsrow/wscol low word) -- never the d value. So
// k_mfma now tracks per-token top1-key and top2-value of s~ (6 VALU/code) and
// cross-lane merges them; if top1-top2 > CERT=2e-4 (5x the ~4e-5 error bound
// validated twice via MARGIN), the exact argmax is PROVABLY top1's code,
// unique, no tie -> wsrow written directly, no rescore. Uncertified tokens
// (~8%, gap < CERT) go to one list and get a FULL 1024-code exact rescore
// with the verbatim 4-chain fmaf formula -- correctness independent of any
// shortlist geometry. Deleted: rbm (2MB), k_rowmax, per-cb lists, and the
// 159us wave-per-candidate rowrescore (round-8 counters: VALU 17.7%, 66MB
// fetch of 16KB-strided broadcast loads). Column path unchanged (validated).
// All rounding-sensitive exact paths verbatim from the passing code.

#define MARGIN 2e-4f
#define CERT   2e-4f

// ---- ws layout (bytes) ----
#define WS_ROW   0         // u64 wsrow[65536]
#define WS_COL   524288    // u64 wscol[1024]
#define WS_CNT   532480    // u32 counts[1024]
#define WS_LOSS  536576    // double loss_acc
#define WS_EN2   536592    // float en2[1024]
#define WS_LCNT  540688    // u32 lcnt
#define WS_ZN2   541696    // float zn2[65536]            (256KB)
#define WS_EBH   803840    // u16 ebf_hi[1024*64]         (128KB)
#define WS_EBL   934912    // u16 ebf_lo[1024*64]         (128KB)
#define WS_LIST  1065984   // u32 list[65536]             (256KB)
#define WS_CBM   1322112   // f32 colbm[1024][512]        (2MB)
#define WS_BYTES 3419264
#define WS_ZERO  540720    // memset range: row/col/cnt/loss/lcnt

typedef __attribute__((ext_vector_type(8))) short short8v;
typedef __attribute__((ext_vector_type(4))) float f32x4;

__device__ __forceinline__ unsigned int f32_ord(float x) {
    unsigned int b = __float_as_uint(x);
    return (b & 0x80000000u) ? ~b : (b | 0x80000000u);
}
__device__ __forceinline__ float ord_f32(unsigned int u) {  // exact inverse
    unsigned int b = (u & 0x80000000u) ? (u & 0x7FFFFFFFu) : ~u;
    return __uint_as_float(b);
}

__device__ __forceinline__ unsigned short f2bf(float f) {  // RNE fp32->bf16
    unsigned int u = __float_as_uint(f);
    return (unsigned short)((u + 0x7FFFu + ((u >> 16) & 1u)) >> 16);
}
__device__ __forceinline__ float bf2f(unsigned short h) {
    return __uint_as_float((unsigned int)h << 16);
}

// numpy pairwise sum of squares over 64 values (verbatim from passing code).
template <typename F>
__device__ __forceinline__ float np_pairwise64_sq(F get) {
    float r[8];
#pragma unroll
    for (int j = 0; j < 8; ++j) {
        float v = get(j);
        r[j] = __fmul_rn(v, v);
    }
#pragma unroll
    for (int i = 8; i < 64; i += 8) {
#pragma unroll
        for (int j = 0; j < 8; ++j) {
            float v = get(i + j);
            r[j] = __fadd_rn(r[j], __fmul_rn(v, v));
        }
    }
    return __fadd_rn(__fadd_rn(__fadd_rn(r[0], r[1]), __fadd_rn(r[2], r[3])),
                     __fadd_rn(__fadd_rn(r[4], r[5]), __fadd_rn(r[6], r[7])));
}

// ---- K0: norms + bf16 hi/lo splits (unchanged, validated 3x) ----
__global__ __launch_bounds__(256) void k_prep(
    const float* __restrict__ z, const float* __restrict__ emb,
    float* __restrict__ en2, float* __restrict__ zn2,
    unsigned int* __restrict__ zbh32, unsigned int* __restrict__ zbl32,
    unsigned int* __restrict__ ebh32, unsigned int* __restrict__ ebl32) {
    const int t = threadIdx.x;
    if (blockIdx.x < 1024) {
        const int n0  = blockIdx.x * 64;
        const int b   = n0 >> 12;
        const int hw0 = n0 & 4095;

        __shared__ float        zl[64][65];   // [ch][tok], pad 65
        __shared__ unsigned int oh[64][33];   // [tok][wd], pad 33
        __shared__ unsigned int ol[64][33];

#pragma unroll
        for (int it = 0; it < 16; ++it) {
            int idx = it * 256 + t;
            int c = idx >> 6, tok = idx & 63;
            zl[c][tok] = z[(size_t)b * 262144 + (size_t)c * 4096 + hw0 + tok];
        }
        __syncthreads();

        const int tk = t & 63, q = t >> 6;
        if (q == 0)
            zn2[n0 + tk] = np_pairwise64_sq([&](int i) { return zl[i][tk]; });

#pragma unroll
        for (int w8 = 0; w8 < 8; ++w8) {
            int wd = q * 8 + w8;
            float z0 = zl[2 * wd][tk], z1 = zl[2 * wd + 1][tk];
            unsigned short h0 = f2bf(z0), h1 = f2bf(z1);
            oh[tk][wd] = (unsigned int)h0 | ((unsigned int)h1 << 16);
            unsigned short l0 = f2bf(__fsub_rn(z0, bf2f(h0)));
            unsigned short l1 = f2bf(__fsub_rn(z1, bf2f(h1)));
            ol[tk][wd] = (unsigned int)l0 | ((unsigned int)l1 << 16);
        }
        __syncthreads();

#pragma unroll
        for (int it = 0; it < 8; ++it) {
            int idx = it * 256 + t;
            int tok = idx >> 5, wd = idx & 31;
            zbh32[(size_t)(n0 + tok) * 32 + wd] = oh[tok][wd];
            zbl32[(size_t)(n0 + tok) * 32 + wd] = ol[tok][wd];
        }
    } else {
        const int k = (blockIdx.x - 1024) * 256 + t;
        const float* a = emb + (size_t)k * 64;
        float ar[64];
#pragma unroll
        for (int i = 0; i < 64; ++i) ar[i] = a[i];
        en2[k] = np_pairwise64_sq([&](int i) { return ar[i]; });
#pragma unroll
        for (int wd = 0; wd < 32; ++wd) {
            float e0 = ar[2 * wd], e1 = ar[2 * wd + 1];
            unsigned short h0 = f2bf(e0), h1 = f2bf(e1);
            ebh32[k * 32 + wd] = (unsigned int)h0 | ((unsigned int)h1 << 16);
            unsigned short l0 = f2bf(__fsub_rn(e0, bf2f(h0)));
            unsigned short l1 = f2bf(__fsub_rn(e1, bf2f(h1)));
            ebl32[k * 32 + wd] = (unsigned int)l0 | ((unsigned int)l1 << 16);
        }
    }
}

// ---- K1: s~ via bf16 MFMA (e LDS dbuf) + per-token top-2 certification ----
// grid 512 x 512 (8 waves). Wave w: tokens tw..tw+15, all 1024 codes.
// Per lane: 4 tokens (kg,j), 1 code (lm) per sub-chunk; 64 codes total.
// Row: per-lane top1/top2 over its 64 codes -> cross-lm merge -> certified
// tokens write wsrow directly; rest go to list. Col: block maxes (unchanged).
__global__ __launch_bounds__(512, 2) void k_mfma(
    const unsigned short* __restrict__ zbh, const unsigned short* __restrict__ zbl,
    const unsigned short* __restrict__ ebh, const unsigned short* __restrict__ ebl,
    const float* __restrict__ zn2, const float* __restrict__ en2,
    float* __restrict__ cbm, unsigned long long* __restrict__ wsrow,
    unsigned int* __restrict__ lcnt, unsigned int* __restrict__ list) {
    const int t = threadIdx.x, l = t & 63, w = t >> 6;
    const int n0 = blockIdx.x * 128;
    const int tw = n0 + w * 16;
    const int lm = l & 15, kg = l >> 4;

    __shared__ __align__(16) unsigned int eh[2][64 * 36];
    __shared__ __align__(16) unsigned int el[2][64 * 36];
    __shared__ float        en2l[1024];
    __shared__ unsigned int cmU[1024];    // column max as f32_ord (atomicMax)

    for (int i = t; i < 1024; i += 512) { en2l[i] = en2[i]; cmU[i] = 0u; }

    const uint4* EH4 = reinterpret_cast<const uint4*>(ebh);
    const uint4* EL4 = reinterpret_cast<const uint4*>(ebl);
    const int scode = t >> 3, swd = (t & 7) * 4;

    {   // stage group 0
        uint4 hv = EH4[t], lv = EL4[t];
        *reinterpret_cast<uint4*>(&eh[0][scode * 36 + swd]) = hv;
        *reinterpret_cast<uint4*>(&el[0][scode * 36 + swd]) = lv;
    }

    const int tok = tw + lm;
    const short8v ah0 = *reinterpret_cast<const short8v*>(zbh + tok * 64 + kg * 8);
    const short8v ah1 = *reinterpret_cast<const short8v*>(zbh + tok * 64 + 32 + kg * 8);
    const short8v al0 = *reinterpret_cast<const short8v*>(zbl + tok * 64 + kg * 8);
    const short8v al1 = *reinterpret_cast<const short8v*>(zbl + tok * 64 + 32 + kg * 8);

    float nzn2[4];
    {
        const float4 zv = *reinterpret_cast<const float4*>(zn2 + tw + kg * 4);
        nzn2[0] = -zv.x; nzn2[1] = -zv.y; nzn2[2] = -zv.z; nzn2[3] = -zv.w;
    }
    float v1[4] = {-3.4e38f, -3.4e38f, -3.4e38f, -3.4e38f};
    float v2[4] = {-3.4e38f, -3.4e38f, -3.4e38f, -3.4e38f};
    int   c1[4] = {0, 0, 0, 0};

    __syncthreads();

    for (int g = 0; g < 16; ++g) {
        const int buf = g & 1;
        const bool pf = (g < 15);
        uint4 hv, lv;
        if (pf) {   // issue next group's loads early; write AFTER compute
            hv = EH4[(g + 1) * 512 + t];
            lv = EL4[(g + 1) * 512 + t];
        }

#pragma unroll
        for (int sc = 0; sc < 4; ++sc) {
            const int cl = sc * 16 + lm;
            const short8v bh0 = *reinterpret_cast<const short8v*>(&eh[buf][cl * 36 + kg * 4]);
            const short8v bh1 = *reinterpret_cast<const short8v*>(&eh[buf][cl * 36 + 16 + kg * 4]);
            const short8v bl0 = *reinterpret_cast<const short8v*>(&el[buf][cl * 36 + kg * 4]);
            const short8v bl1 = *reinterpret_cast<const short8v*>(&el[buf][cl * 36 + 16 + kg * 4]);

            f32x4 ahh = {0.f, 0.f, 0.f, 0.f};
            f32x4 ahl = {0.f, 0.f, 0.f, 0.f};
            f32x4 alh = {0.f, 0.f, 0.f, 0.f};
            ahh = __builtin_amdgcn_mfma_f32_16x16x32_bf16(ah0, bh0, ahh, 0, 0, 0);
            ahh = __builtin_amdgcn_mfma_f32_16x16x32_bf16(ah1, bh1, ahh, 0, 0, 0);
            ahl = __builtin_amdgcn_mfma_f32_16x16x32_bf16(ah0, bl0, ahl, 0, 0, 0);
            ahl = __builtin_amdgcn_mfma_f32_16x16x32_bf16(ah1, bl1, ahl, 0, 0, 0);
            alh = __builtin_amdgcn_mfma_f32_16x16x32_bf16(al0, bh0, alh, 0, 0, 0);
            alh = __builtin_amdgcn_mfma_f32_16x16x32_bf16(al1, bh1, alh, 0, 0, 0);

            const int code = g * 64 + cl;
            const float en2v = en2l[code];
            float cm = -3.4e38f;
#pragma unroll
            for (int j = 0; j < 4; ++j) {
                float acc = __fadd_rn(__fadd_rn(ahh[j], ahl[j]), alh[j]);
                float s = __fadd_rn(__fsub_rn(nzn2[j], en2v), 2.0f * acc);
                // per-lane top-2 (codes ascend -> strict > keeps smallest)
                if (s > v1[j]) { v2[j] = v1[j]; v1[j] = s; c1[j] = code; }
                else if (s > v2[j]) { v2[j] = s; }
                cm = fmaxf(cm, s);
            }
            cm = fmaxf(cm, __shfl_xor(cm, 16, 64));
            cm = fmaxf(cm, __shfl_xor(cm, 32, 64));
            if (l < 16) atomicMax(&cmU[code], f32_ord(cm));
        }

        if (pf) {
            *reinterpret_cast<uint4*>(&eh[buf ^ 1][scode * 36 + swd]) = hv;
            *reinterpret_cast<uint4*>(&el[buf ^ 1][scode * 36 + swd]) = lv;
        }
        __syncthreads();
    }

    // ---- row finalize: merge top-2 across the 16 lm-lanes, certify ----
#pragma unroll
    for (int j = 0; j < 4; ++j) {
        unsigned long long key =
            ((unsigned long long)f32_ord(v1[j]) << 32) |
            (unsigned long long)(unsigned int)(~(unsigned int)c1[j]);
        float w2 = v2[j];
#pragma unroll
        for (int m = 1; m < 16; m <<= 1) {
            unsigned long long ok = __shfl_xor(key, m, 64);
            float ov2 = __shfl_xor(w2, m, 64);
            unsigned long long lk = (key < ok) ? key : ok;   // losing top1
            float lv2 = ord_f32((unsigned int)(lk >> 32));
            w2 = fmaxf(fmaxf(w2, ov2), lv2);
            key = (key > ok) ? key : ok;                      // ties: smaller c
        }
        if (lm == 0) {
            const int tn = tw + kg * 4 + j;
            float v1m = ord_f32((unsigned int)(key >> 32));
            if (__fsub_rn(v1m, w2) > CERT) {
                wsrow[tn] = key;      // certified: provably exact argmax index
            } else {
                unsigned int p = atomicAdd(lcnt, 1u);
                list[p] = (unsigned int)tn;
            }
        }
    }

    for (int code = t; code < 1024; code += 512)
        cbm[(size_t)code * 512 + blockIdx.x] = ord_f32(cmU[code]);
}

// ---- K2: full exact row rescore for uncertified tokens ----
// grid (64, 16): blockIdx.y = 64-code partition (k wave-uniform -> s_load),
// grid-stride over the list. Verbatim 4-chain fmaf; atomicMax w/ tie keys.
__global__ __launch_bounds__(256) void k_rowrescore(
    const float* __restrict__ z, const float* __restrict__ emb,
    const float* __restrict__ zn2, const float* __restrict__ en2,
    const unsigned int* __restrict__ list, const unsigned int* __restrict__ lcnt,
    unsigned long long* __restrict__ wsrow) {
    const unsigned int cnt = *lcnt;
    const int k0 = blockIdx.y * 64;
    const float4* E4 = reinterpret_cast<const float4*>(emb);
    for (unsigned int i = blockIdx.x * 256 + threadIdx.x; i < cnt;
         i += 64 * 256) {
        const int n = (int)list[i];
        const int b = n >> 12, hw = n & 4095;
        const float* zp = z + (size_t)b * 262144 + hw;
        const float nz = -zn2[n];
        unsigned long long best = 0ull;
        for (int kk = 0; kk < 64; ++kk) {
            const int k = k0 + kk;                   // wave-uniform -> s_load
            const float4* ek = E4 + (size_t)k * 16;
            float c0 = 0.f, c1 = 0.f, c2 = 0.f, c3 = 0.f;
#pragma unroll
            for (int j = 0; j < 16; ++j) {
                float4 e = ek[j];
                c0 = fmaf(e.x, zp[(size_t)(4 * j + 0) * 4096], c0);
                c1 = fmaf(e.y, zp[(size_t)(4 * j + 1) * 4096], c1);
                c2 = fmaf(e.z, zp[(size_t)(4 * j + 2) * 4096], c2);
                c3 = fmaf(e.w, zp[(size_t)(4 * j + 3) * 4096], c3);
            }
            float dot = (c0 + c1) + (c2 + c3);
            float d = __fadd_rn(__fsub_rn(nz, en2[k]), 2.0f * dot);
            unsigned long long key =
                ((unsigned long long)f32_ord(d) << 32) |
                (unsigned long long)(unsigned int)(~(unsigned int)k);
            if (key > best) best = key;   // ties: larger key = smaller k
        }
        atomicMax(&wsrow[n], best);
    }
}

// ---- K3: exact column rescore over candidate token-groups (validated) ----
__global__ __launch_bounds__(256) void k_colrescore(
    const float* __restrict__ z, const float* __restrict__ emb,
    const float* __restrict__ zn2, const float* __restrict__ en2,
    const float* __restrict__ cbm, unsigned long long* __restrict__ wscol) {
    const int k = blockIdx.x, t = threadIdx.x;
    __shared__ float red[256];
    __shared__ int   hlist[512];
    __shared__ int   hcnt;
    float a  = cbm[(size_t)k * 512 + t];
    float b2 = cbm[(size_t)k * 512 + 256 + t];
    red[t] = fmaxf(a, b2);
    if (t == 0) hcnt = 0;
    __syncthreads();
    for (int st = 128; st; st >>= 1) {
        if (t < st) red[t] = fmaxf(red[t], red[t + st]);
        __syncthreads();
    }
    const float thr = red[0] - MARGIN;
    if (a >= thr)  { int p = atomicAdd(&hcnt, 1); hlist[p] = t; }
    if (b2 >= thr) { int p = atomicAdd(&hcnt, 1); hlist[p] = t + 256; }
    __syncthreads();
    const int hc = hcnt;
    const float en2k = en2[k];
    const float4* ek = reinterpret_cast<const float4*>(emb + (size_t)k * 64);

    for (int h = 0; h < hc; ++h) {
        const int g = hlist[h];
        if (t < 128) {
            const int n = g * 128 + t;
            const int b = n >> 12, hw = n & 4095;
            const float* zp = z + (size_t)b * 262144 + hw;
            float c0 = 0.f, c1 = 0.f, c2 = 0.f, c3 = 0.f;
#pragma unroll
            for (int j = 0; j < 16; ++j) {
                float4 e = ek[j];
                c0 = fmaf(e.x, zp[(size_t)(4 * j + 0) * 4096], c0);
                c1 = fmaf(e.y, zp[(size_t)(4 * j + 1) * 4096], c1);
                c2 = fmaf(e.z, zp[(size_t)(4 * j + 2) * 4096], c2);
                c3 = fmaf(e.w, zp[(size_t)(4 * j + 3) * 4096], c3);
            }
            float dot = (c0 + c1) + (c2 + c3);
            float d = __fadd_rn(__fsub_rn(-zn2[n], en2k), 2.0f * dot);
            unsigned long long key =
                ((unsigned long long)f32_ord(d) << 32) |
                (unsigned long long)(unsigned int)(~(unsigned int)n);
#pragma unroll
            for (int m = 1; m < 64; m <<= 1) {
                unsigned long long o = __shfl_xor(key, m, 64);
                if (o > key) key = o;    // ties: larger key = smaller n
            }
            if ((t & 63) == 0) atomicMax(&wscol[k], key);
        }
    }
}

// ---- K4: per-token outputs: z_q, indices, hist, loss (unchanged) ----
__global__ __launch_bounds__(256) void k_tokens(
    const float* __restrict__ z, const float* __restrict__ emb,
    const unsigned long long* __restrict__ wsrow,
    unsigned int* __restrict__ counts, double* __restrict__ loss_acc,
    float* __restrict__ out_zq, float* __restrict__ out_idx) {
    const int n  = blockIdx.x * 256 + threadIdx.x;
    const int b  = n >> 12;
    const int hw = n & 4095;

    unsigned long long key = wsrow[n];
    int idx = (int)(~(unsigned int)(key & 0xFFFFFFFFull));
    out_idx[n] = (float)idx;
    atomicAdd(&counts[idx], 1u);

    const float* zp = z + (size_t)b * 262144 + hw;
    float*       op = out_zq + (size_t)b * 262144 + hw;
    const float* ep = emb + (size_t)idx * 64;

    double ls = 0.0;
#pragma unroll
    for (int c = 0; c < 64; ++c) {
        float zc   = zp[(size_t)c * 4096];
        float eq   = ep[c];
        float diff = __fsub_rn(eq, zc);              // fl(z_q - zc)
        float sq   = __fmul_rn(diff, diff);
        ls += (double)sq;
        op[(size_t)c * 4096] = __fadd_rn(zc, diff);  // zc + fl(z_q - zc)
    }

    __shared__ double sred[256];
    sred[threadIdx.x] = ls;
    __syncthreads();
    for (int st = 128; st; st >>= 1) {
        if (threadIdx.x < st) sred[threadIdx.x] += sred[threadIdx.x + st];
        __syncthreads();
    }
    if (threadIdx.x == 0) atomicAdd(loss_acc, sred[0]);
}

// ---- K5: tail — new embedding + scalars (unchanged) ----
__global__ __launch_bounds__(1024) void k_tail(
    const float* __restrict__ z, const float* __restrict__ emb,
    const float* __restrict__ embed_prob,
    const unsigned long long* __restrict__ wscol,
    const unsigned int* __restrict__ counts,
    const double* __restrict__ loss_acc,
    float* __restrict__ out_newemb, float* __restrict__ out_loss,
    float* __restrict__ out_perp, float* __restrict__ out_prob) {
    const int k = blockIdx.x * 16 + (threadIdx.x >> 6);
    const int c = threadIdx.x & 63;

    float avg  = (float)counts[k] * (1.0f / 65536.0f);
    float pnew = __fadd_rn(__fmul_rn(embed_prob[k], 0.99f),
                           __fmul_rn(0.01f, avg));
    float tt = __fdiv_rn(__fmul_rn(__fmul_rn(pnew, 1024.0f), 10.0f), 0.01f);
    float dk = expf(__fsub_rn(-tt, 1e-3f));
    float omd = __fsub_rn(1.0f, dk);

    unsigned long long ck = wscol[k];
    int cn  = (int)(~(unsigned int)(ck & 0xFFFFFFFFull));
    int cb  = cn >> 12;
    int chw = cn & 4095;

    float rf = z[(size_t)cb * 262144 + (size_t)c * 4096 + chw];
    float e  = emb[(size_t)k * 64 + c];
    out_newemb[(size_t)k * 64 + c] =
        __fadd_rn(__fmul_rn(e, omd), __fmul_rn(rf, dk));

    if (blockIdx.x == 0) {
        const int q = threadIdx.x;

        float avg2  = (float)counts[q] * (1.0f / 65536.0f);
        float pnew2 = __fadd_rn(__fmul_rn(embed_prob[q], 0.99f),
                                __fmul_rn(0.01f, avg2));
        out_prob[q] = pnew2;

        float term = __fmul_rn(avg2, logf(__fadd_rn(avg2, 1e-10f)));
        __shared__ double red[1024];
        red[q] = (double)term;
        __syncthreads();
        for (int st = 512; st; st >>= 1) {
            if (q < st) red[q] += red[q + st];
            __syncthreads();
        }
        if (q == 0) {
            float s32 = (float)red[0];
            out_perp[0] = expf(-s32);
            double lm = loss_acc[0] / 4194304.0;
            float  m  = (float)lm;
            out_loss[0] = __fadd_rn(__fmul_rn(0.25f, m), m);  // BETA*m + m
        }
    }
}

extern "C" void kernel_launch(void* const* d_in, const int* in_sizes, int n_in,
                              void* d_out, int out_size, void* d_ws, size_t ws_size,
                              hipStream_t stream) {
    const float* z    = (const float*)d_in[0];   // 16*64*64*64
    const float* emb  = (const float*)d_in[1];   // 1024*64
    const float* prob = (const float*)d_in[2];   // 1024

    float* out        = (float*)d_out;
    float* out_zq     = out;                 // 4194304 floats (16.777 MB)
    float* out_loss   = out + 4194304;
    float* out_perp   = out + 4194305;
    float* out_newemb = out + 4194306;
    float* out_prob   = out + 4259842;
    float* out_idx    = out + 4260866;

    char* ws = (char*)d_ws;
    unsigned long long* wsrow = (unsigned long long*)(ws + WS_ROW);
    unsigned long long* wscol = (unsigned long long*)(ws + WS_COL);
    unsigned int*       cnts  = (unsigned int*)(ws + WS_CNT);
    double*             lacc  = (double*)(ws + WS_LOSS);
    float*              en2   = (float*)(ws + WS_EN2);
    unsigned int*       lcnt  = (unsigned int*)(ws + WS_LCNT);
    float*              zn2   = (float*)(ws + WS_ZN2);
    unsigned short*     ebh   = (unsigned short*)(ws + WS_EBH);
    unsigned short*     ebl   = (unsigned short*)(ws + WS_EBL);
    unsigned int*       list  = (unsigned int*)(ws + WS_LIST);
    float*              cbm   = (float*)(ws + WS_CBM);

    // out_zq doubles as scratch before k_tokens rewrites it:
    //   zbf_hi u16[4.2M] @ bytes [0, 8388608)
    //   zbf_lo u16[4.2M] @ bytes [8388608, 16777216)
    unsigned short* zbh = (unsigned short*)out_zq;
    unsigned short* zbl = (unsigned short*)((char*)out_zq + 8388608);

    hipMemsetAsync(d_ws, 0, WS_ZERO, stream);

    hipLaunchKernelGGL(k_prep, dim3(1028), dim3(256), 0, stream,
                       z, emb, en2, zn2,
                       (unsigned int*)zbh, (unsigned int*)zbl,
                       (unsigned int*)ebh, (unsigned int*)ebl);
    hipLaunchKernelGGL(k_mfma, dim3(512), dim3(512), 0, stream,
                       zbh, zbl, ebh, ebl, zn2, en2, cbm, wsrow, lcnt, list);
    hipLaunchKernelGGL(k_colrescore, dim3(1024), dim3(256), 0, stream,
                       z, emb, zn2, en2, cbm, wscol);
    hipLaunchKernelGGL(k_rowrescore, dim3(64, 16), dim3(256), 0, stream,
                       z, emb, zn2, en2, list, lcnt, wsrow);
    hipLaunchKernelGGL(k_tokens, dim3(256), dim3(256), 0, stream,
                       z, emb, wsrow, cnts, lacc, out_zq, out_idx);
    hipLaunchKernelGGL(k_tail, dim3(64), dim3(1024), 0, stream,
                       z, emb, prob, wscol, cnts, lacc,
                       out_newemb, out_loss, out_perp, out_prob);
}

// Round 10
// 259.372 us; speedup vs baseline: 1.5603x; 1.0754x over previous
//
#include <hip/hip_runtime.h>

// VectorQuantiser forward, MI355X fp32.
// N=65536 tokens (16x64x64, channel dim 64 strided by 4096), K=1024 codes, D=64.
//
// Round 12: k_mfma VALU/LDS diet. Round-9 counters: k_mfma 95.5us, MfmaUtil
// 10.8%, VALUBusy 38%, SQ_LDS_BANK_CONFLICT 4194304 = exactly 16 per cmU
// atomicMax issue (LDS RMW serializes its 16 lanes). Fixes:
//  - colmax[8][1024] per-wave rows, plain ds_write (each (wave,code) written
//    exactly once -> no RMW), 8-way fmax reduce at the end. Conflicts -> 0.
//  - hl+lh merged into ONE 4-deep MFMA chain (a2); s~ = fmaf(2, a1+a2, base).
//    s~ is the approximate score; the |s~-d| <= ~4e-5 bound (validated by two
//    passing rounds) only tightens under fma, and every consumer (top-2 CERT,
//    cbm MARGIN) uses s~ consistently -> outputs bit-identical by the same
//    shortlist/certificate argument.
//  - top-2 in min/max form: v2=max(min(s,v1),v2), v1=max(v1,s), c1 by cndmask
//    on the old v1 -- exact same values as the branchy version, fewer ops.
//  - s_setprio(1) around the MFMA cluster (T5).
//  - k_colrescore + k_rowrescore merged into one k_rescore launch (disjoint
//    block ranges, bodies verbatim).
// All exact fp paths (k_prep norms/splits, rescore 4-chain fmaf dots, key
// packing, tie semantics, k_tokens, k_tail) verbatim from the passing code.

#define MARGIN 2e-4f
#define CERT   2e-4f

// ---- ws layout (bytes) ----
#define WS_ROW   0         // u64 wsrow[65536]
#define WS_COL   524288    // u64 wscol[1024]
#define WS_CNT   532480    // u32 counts[1024]
#define WS_LOSS  536576    // double loss_acc
#define WS_EN2   536592    // float en2[1024]
#define WS_LCNT  540688    // u32 lcnt
#define WS_ZN2   541696    // float zn2[65536]            (256KB)
#define WS_EBH   803840    // u16 ebf_hi[1024*64]         (128KB)
#define WS_EBL   934912    // u16 ebf_lo[1024*64]         (128KB)
#define WS_LIST  1065984   // u32 list[65536]             (256KB)
#define WS_CBM   1322112   // f32 colbm[1024][512]        (2MB)
#define WS_BYTES 3419264
#define WS_ZERO  540720    // memset range: row/col/cnt/loss/lcnt

typedef __attribute__((ext_vector_type(8))) short short8v;
typedef __attribute__((ext_vector_type(4))) float f32x4;

__device__ __forceinline__ unsigned int f32_ord(float x) {
    unsigned int b = __float_as_uint(x);
    return (b & 0x80000000u) ? ~b : (b | 0x80000000u);
}
__device__ __forceinline__ float ord_f32(unsigned int u) {  // exact inverse
    unsigned int b = (u & 0x80000000u) ? (u & 0x7FFFFFFFu) : ~u;
    return __uint_as_float(b);
}

__device__ __forceinline__ unsigned short f2bf(float f) {  // RNE fp32->bf16
    unsigned int u = __float_as_uint(f);
    return (unsigned short)((u + 0x7FFFu + ((u >> 16) & 1u)) >> 16);
}
__device__ __forceinline__ float bf2f(unsigned short h) {
    return __uint_as_float((unsigned int)h << 16);
}

// numpy pairwise sum of squares over 64 values (verbatim from passing code).
template <typename F>
__device__ __forceinline__ float np_pairwise64_sq(F get) {
    float r[8];
#pragma unroll
    for (int j = 0; j < 8; ++j) {
        float v = get(j);
        r[j] = __fmul_rn(v, v);
    }
#pragma unroll
    for (int i = 8; i < 64; i += 8) {
#pragma unroll
        for (int j = 0; j < 8; ++j) {
            float v = get(i + j);
            r[j] = __fadd_rn(r[j], __fmul_rn(v, v));
        }
    }
    return __fadd_rn(__fadd_rn(__fadd_rn(r[0], r[1]), __fadd_rn(r[2], r[3])),
                     __fadd_rn(__fadd_rn(r[4], r[5]), __fadd_rn(r[6], r[7])));
}

// ---- K0: norms + bf16 hi/lo splits (unchanged, validated 4x) ----
__global__ __launch_bounds__(256) void k_prep(
    const float* __restrict__ z, const float* __restrict__ emb,
    float* __restrict__ en2, float* __restrict__ zn2,
    unsigned int* __restrict__ zbh32, unsigned int* __restrict__ zbl32,
    unsigned int* __restrict__ ebh32, unsigned int* __restrict__ ebl32) {
    const int t = threadIdx.x;
    if (blockIdx.x < 1024) {
        const int n0  = blockIdx.x * 64;
        const int b   = n0 >> 12;
        const int hw0 = n0 & 4095;

        __shared__ float        zl[64][65];   // [ch][tok], pad 65
        __shared__ unsigned int oh[64][33];   // [tok][wd], pad 33
        __shared__ unsigned int ol[64][33];

#pragma unroll
        for (int it = 0; it < 16; ++it) {
            int idx = it * 256 + t;
            int c = idx >> 6, tok = idx & 63;
            zl[c][tok] = z[(size_t)b * 262144 + (size_t)c * 4096 + hw0 + tok];
        }
        __syncthreads();

        const int tk = t & 63, q = t >> 6;
        if (q == 0)
            zn2[n0 + tk] = np_pairwise64_sq([&](int i) { return zl[i][tk]; });

#pragma unroll
        for (int w8 = 0; w8 < 8; ++w8) {
            int wd = q * 8 + w8;
            float z0 = zl[2 * wd][tk], z1 = zl[2 * wd + 1][tk];
            unsigned short h0 = f2bf(z0), h1 = f2bf(z1);
            oh[tk][wd] = (unsigned int)h0 | ((unsigned int)h1 << 16);
            unsigned short l0 = f2bf(__fsub_rn(z0, bf2f(h0)));
            unsigned short l1 = f2bf(__fsub_rn(z1, bf2f(h1)));
            ol[tk][wd] = (unsigned int)l0 | ((unsigned int)l1 << 16);
        }
        __syncthreads();

#pragma unroll
        for (int it = 0; it < 8; ++it) {
            int idx = it * 256 + t;
            int tok = idx >> 5, wd = idx & 31;
            zbh32[(size_t)(n0 + tok) * 32 + wd] = oh[tok][wd];
            zbl32[(size_t)(n0 + tok) * 32 + wd] = ol[tok][wd];
        }
    } else {
        const int k = (blockIdx.x - 1024) * 256 + t;
        const float* a = emb + (size_t)k * 64;
        float ar[64];
#pragma unroll
        for (int i = 0; i < 64; ++i) ar[i] = a[i];
        en2[k] = np_pairwise64_sq([&](int i) { return ar[i]; });
#pragma unroll
        for (int wd = 0; wd < 32; ++wd) {
            float e0 = ar[2 * wd], e1 = ar[2 * wd + 1];
            unsigned short h0 = f2bf(e0), h1 = f2bf(e1);
            ebh32[k * 32 + wd] = (unsigned int)h0 | ((unsigned int)h1 << 16);
            unsigned short l0 = f2bf(__fsub_rn(e0, bf2f(h0)));
            unsigned short l1 = f2bf(__fsub_rn(e1, bf2f(h1)));
            ebl32[k * 32 + wd] = (unsigned int)l0 | ((unsigned int)l1 << 16);
        }
    }
}

// ---- K1: s~ via bf16 MFMA (e LDS dbuf) + per-token top-2 certification ----
// grid 512 x 512 (8 waves). Wave w: tokens tw..tw+15, all 1024 codes.
// Two MFMA chains: a1 = hh (2-deep), a2 = hl+lh (4-deep).
// Row: per-lane top1/top2 -> cross-lm merge -> certified tokens write wsrow
// directly; rest listed. Col: per-wave colmax rows (plain writes, no RMW).
__global__ __launch_bounds__(512, 2) void k_mfma(
    const unsigned short* __restrict__ zbh, const unsigned short* __restrict__ zbl,
    const unsigned short* __restrict__ ebh, const unsigned short* __restrict__ ebl,
    const float* __restrict__ zn2, const float* __restrict__ en2,
    float* __restrict__ cbm, unsigned long long* __restrict__ wsrow,
    unsigned int* __restrict__ lcnt, unsigned int* __restrict__ list) {
    const int t = threadIdx.x, l = t & 63, w = t >> 6;
    const int n0 = blockIdx.x * 128;
    const int tw = n0 + w * 16;
    const int lm = l & 15, kg = l >> 4;

    __shared__ __align__(16) unsigned int eh[2][64 * 36];
    __shared__ __align__(16) unsigned int el[2][64 * 36];
    __shared__ float en2l[1024];
    __shared__ float colmax[8][1024];   // per-wave row: exclusive plain writes

    for (int i = t; i < 1024; i += 512) en2l[i] = en2[i];

    const uint4* EH4 = reinterpret_cast<const uint4*>(ebh);
    const uint4* EL4 = reinterpret_cast<const uint4*>(ebl);
    const int scode = t >> 3, swd = (t & 7) * 4;

    {   // stage group 0
        uint4 hv = EH4[t], lv = EL4[t];
        *reinterpret_cast<uint4*>(&eh[0][scode * 36 + swd]) = hv;
        *reinterpret_cast<uint4*>(&el[0][scode * 36 + swd]) = lv;
    }

    const int tok = tw + lm;
    const short8v ah0 = *reinterpret_cast<const short8v*>(zbh + tok * 64 + kg * 8);
    const short8v ah1 = *reinterpret_cast<const short8v*>(zbh + tok * 64 + 32 + kg * 8);
    const short8v al0 = *reinterpret_cast<const short8v*>(zbl + tok * 64 + kg * 8);
    const short8v al1 = *reinterpret_cast<const short8v*>(zbl + tok * 64 + 32 + kg * 8);

    float nzn2[4];
    {
        const float4 zv = *reinterpret_cast<const float4*>(zn2 + tw + kg * 4);
        nzn2[0] = -zv.x; nzn2[1] = -zv.y; nzn2[2] = -zv.z; nzn2[3] = -zv.w;
    }
    float v1[4] = {-3.4e38f, -3.4e38f, -3.4e38f, -3.4e38f};
    float v2[4] = {-3.4e38f, -3.4e38f, -3.4e38f, -3.4e38f};
    int   c1[4] = {0, 0, 0, 0};

    __syncthreads();

    for (int g = 0; g < 16; ++g) {
        const int buf = g & 1;
        const bool pf = (g < 15);
        uint4 hv, lv;
        if (pf) {   // issue next group's loads early; write AFTER compute
            hv = EH4[(g + 1) * 512 + t];
            lv = EL4[(g + 1) * 512 + t];
        }

#pragma unroll
        for (int sc = 0; sc < 4; ++sc) {
            const int cl = sc * 16 + lm;
            const short8v bh0 = *reinterpret_cast<const short8v*>(&eh[buf][cl * 36 + kg * 4]);
            const short8v bh1 = *reinterpret_cast<const short8v*>(&eh[buf][cl * 36 + 16 + kg * 4]);
            const short8v bl0 = *reinterpret_cast<const short8v*>(&el[buf][cl * 36 + kg * 4]);
            const short8v bl1 = *reinterpret_cast<const short8v*>(&el[buf][cl * 36 + 16 + kg * 4]);

            f32x4 a1 = {0.f, 0.f, 0.f, 0.f};
            f32x4 a2 = {0.f, 0.f, 0.f, 0.f};
            __builtin_amdgcn_s_setprio(1);
            a1 = __builtin_amdgcn_mfma_f32_16x16x32_bf16(ah0, bh0, a1, 0, 0, 0);
            a1 = __builtin_amdgcn_mfma_f32_16x16x32_bf16(ah1, bh1, a1, 0, 0, 0);
            a2 = __builtin_amdgcn_mfma_f32_16x16x32_bf16(ah0, bl0, a2, 0, 0, 0);
            a2 = __builtin_amdgcn_mfma_f32_16x16x32_bf16(ah1, bl1, a2, 0, 0, 0);
            a2 = __builtin_amdgcn_mfma_f32_16x16x32_bf16(al0, bh0, a2, 0, 0, 0);
            a2 = __builtin_amdgcn_mfma_f32_16x16x32_bf16(al1, bh1, a2, 0, 0, 0);
            __builtin_amdgcn_s_setprio(0);

            const int code = g * 64 + cl;
            const float en2v = en2l[code];
            float cm = -3.4e38f;
#pragma unroll
            for (int j = 0; j < 4; ++j) {
                float acc  = __fadd_rn(a1[j], a2[j]);
                float base = __fsub_rn(nzn2[j], en2v);
                float s    = fmaf(2.0f, acc, base);
                // top-2, min/max form (identical values to the branchy version)
                bool gt = s > v1[j];
                v2[j] = fmaxf(fminf(s, v1[j]), v2[j]);
                v1[j] = fmaxf(v1[j], s);
                c1[j] = gt ? code : c1[j];
                cm = fmaxf(cm, s);
            }
            cm = fmaxf(cm, __shfl_xor(cm, 16, 64));
            cm = fmaxf(cm, __shfl_xor(cm, 32, 64));
            if (l < 16) colmax[w][code] = cm;   // exclusive writer, no RMW
        }

        if (pf) {
            *reinterpret_cast<uint4*>(&eh[buf ^ 1][scode * 36 + swd]) = hv;
            *reinterpret_cast<uint4*>(&el[buf ^ 1][scode * 36 + swd]) = lv;
        }
        __syncthreads();
    }

    // ---- row finalize: merge top-2 across the 16 lm-lanes, certify ----
#pragma unroll
    for (int j = 0; j < 4; ++j) {
        unsigned long long key =
            ((unsigned long long)f32_ord(v1[j]) << 32) |
            (unsigned long long)(unsigned int)(~(unsigned int)c1[j]);
        float w2 = v2[j];
#pragma unroll
        for (int m = 1; m < 16; m <<= 1) {
            unsigned long long ok = __shfl_xor(key, m, 64);
            float ov2 = __shfl_xor(w2, m, 64);
            unsigned long long lk = (key < ok) ? key : ok;   // losing top1
            float lv2 = ord_f32((unsigned int)(lk >> 32));
            w2 = fmaxf(fmaxf(w2, ov2), lv2);
            key = (key > ok) ? key : ok;                      // ties: smaller c
        }
        if (lm == 0) {
            const int tn = tw + kg * 4 + j;
            float v1m = ord_f32((unsigned int)(key >> 32));
            if (__fsub_rn(v1m, w2) > CERT) {
                wsrow[tn] = key;      // certified: provably exact argmax index
            } else {
                unsigned int p = atomicAdd(lcnt, 1u);
                list[p] = (unsigned int)tn;
            }
        }
    }

    // ---- col write-out: reduce 8 wave-rows ----
    for (int code = t; code < 1024; code += 512) {
        float m = colmax[0][code];
#pragma unroll
        for (int q = 1; q < 8; ++q) m = fmaxf(m, colmax[q][code]);
        cbm[(size_t)code * 512 + blockIdx.x] = m;
    }
}

// ---- K2: merged exact rescore (col part: blocks 0..1023; row: 1024..2047) ----
// Both bodies verbatim from the passing round-9 kernels.
__global__ __launch_bounds__(256) void k_rescore(
    const float* __restrict__ z, const float* __restrict__ emb,
    const float* __restrict__ zn2, const float* __restrict__ en2,
    const float* __restrict__ cbm,
    const unsigned int* __restrict__ list, const unsigned int* __restrict__ lcnt,
    unsigned long long* __restrict__ wscol,
    unsigned long long* __restrict__ wsrow) {
    const int t = threadIdx.x;
    if (blockIdx.x < 1024) {
        // -- column rescore: block per code --
        const int k = blockIdx.x;
        __shared__ float red[256];
        __shared__ int   hlist[512];
        __shared__ int   hcnt;
        float a  = cbm[(size_t)k * 512 + t];
        float b2 = cbm[(size_t)k * 512 + 256 + t];
        red[t] = fmaxf(a, b2);
        if (t == 0) hcnt = 0;
        __syncthreads();
        for (int st = 128; st; st >>= 1) {
            if (t < st) red[t] = fmaxf(red[t], red[t + st]);
            __syncthreads();
        }
        const float thr = red[0] - MARGIN;
        if (a >= thr)  { int p = atomicAdd(&hcnt, 1); hlist[p] = t; }
        if (b2 >= thr) { int p = atomicAdd(&hcnt, 1); hlist[p] = t + 256; }
        __syncthreads();
        const int hc = hcnt;
        const float en2k = en2[k];
        const float4* ek = reinterpret_cast<const float4*>(emb + (size_t)k * 64);

        for (int h = 0; h < hc; ++h) {
            const int g = hlist[h];
            if (t < 128) {
                const int n = g * 128 + t;
                const int b = n >> 12, hw = n & 4095;
                const float* zp = z + (size_t)b * 262144 + hw;
                float c0 = 0.f, c1 = 0.f, c2 = 0.f, c3 = 0.f;
#pragma unroll
                for (int j = 0; j < 16; ++j) {
                    float4 e = ek[j];
                    c0 = fmaf(e.x, zp[(size_t)(4 * j + 0) * 4096], c0);
                    c1 = fmaf(e.y, zp[(size_t)(4 * j + 1) * 4096], c1);
                    c2 = fmaf(e.z, zp[(size_t)(4 * j + 2) * 4096], c2);
                    c3 = fmaf(e.w, zp[(size_t)(4 * j + 3) * 4096], c3);
                }
                float dot = (c0 + c1) + (c2 + c3);
                float d = __fadd_rn(__fsub_rn(-zn2[n], en2k), 2.0f * dot);
                unsigned long long key =
                    ((unsigned long long)f32_ord(d) << 32) |
                    (unsigned long long)(unsigned int)(~(unsigned int)n);
#pragma unroll
                for (int m = 1; m < 64; m <<= 1) {
                    unsigned long long o = __shfl_xor(key, m, 64);
                    if (o > key) key = o;    // ties: larger key = smaller n
                }
                if ((t & 63) == 0) atomicMax(&wscol[k], key);
            }
        }
    } else {
        // -- row rescore for uncertified tokens --
        const int bid2 = blockIdx.x - 1024;
        const int k0 = (bid2 >> 6) * 64;     // 16 partitions of 64 codes
        const unsigned int cnt = *lcnt;
        const float4* E4 = reinterpret_cast<const float4*>(emb);
        for (unsigned int i = (unsigned int)(bid2 & 63) * 256 + t; i < cnt;
             i += 64 * 256) {
            const int n = (int)list[i];
            const int b = n >> 12, hw = n & 4095;
            const float* zp = z + (size_t)b * 262144 + hw;
            const float nz = -zn2[n];
            unsigned long long best = 0ull;
            for (int kk = 0; kk < 64; ++kk) {
                const int k = k0 + kk;               // wave-uniform -> s_load
                const float4* ek = E4 + (size_t)k * 16;
                float c0 = 0.f, c1 = 0.f, c2 = 0.f, c3 = 0.f;
#pragma unroll
                for (int j = 0; j < 16; ++j) {
                    float4 e = ek[j];
                    c0 = fmaf(e.x, zp[(size_t)(4 * j + 0) * 4096], c0);
                    c1 = fmaf(e.y, zp[(size_t)(4 * j + 1) * 4096], c1);
                    c2 = fmaf(e.z, zp[(size_t)(4 * j + 2) * 4096], c2);
                    c3 = fmaf(e.w, zp[(size_t)(4 * j + 3) * 4096], c3);
                }
                float dot = (c0 + c1) + (c2 + c3);
                float d = __fadd_rn(__fsub_rn(nz, en2[k]), 2.0f * dot);
                unsigned long long key =
                    ((unsigned long long)f32_ord(d) << 32) |
                    (unsigned long long)(unsigned int)(~(unsigned int)k);
                if (key > best) best = key;   // ties: larger key = smaller k
            }
            atomicMax(&wsrow[n], best);
        }
    }
}

// ---- K3: per-token outputs: z_q, indices, hist, loss (unchanged) ----
__global__ __launch_bounds__(256) void k_tokens(
    const float* __restrict__ z, const float* __restrict__ emb,
    const unsigned long long* __restrict__ wsrow,
    unsigned int* __restrict__ counts, double* __restrict__ loss_acc,
    float* __restrict__ out_zq, float* __restrict__ out_idx) {
    const int n  = blockIdx.x * 256 + threadIdx.x;
    const int b  = n >> 12;
    const int hw = n & 4095;

    unsigned long long key = wsrow[n];
    int idx = (int)(~(unsigned int)(key & 0xFFFFFFFFull));
    out_idx[n] = (float)idx;
    atomicAdd(&counts[idx], 1u);

    const float* zp = z + (size_t)b * 262144 + hw;
    float*       op = out_zq + (size_t)b * 262144 + hw;
    const float* ep = emb + (size_t)idx * 64;

    double ls = 0.0;
#pragma unroll
    for (int c = 0; c < 64; ++c) {
        float zc   = zp[(size_t)c * 4096];
        float eq   = ep[c];
        float diff = __fsub_rn(eq, zc);              // fl(z_q - zc)
        float sq   = __fmul_rn(diff, diff);
        ls += (double)sq;
        op[(size_t)c * 4096] = __fadd_rn(zc, diff);  // zc + fl(z_q - zc)
    }

    __shared__ double sred[256];
    sred[threadIdx.x] = ls;
    __syncthreads();
    for (int st = 128; st; st >>= 1) {
        if (threadIdx.x < st) sred[threadIdx.x] += sred[threadIdx.x + st];
        __syncthreads();
    }
    if (threadIdx.x == 0) atomicAdd(loss_acc, sred[0]);
}

// ---- K4: tail — new embedding + scalars (unchanged) ----
__global__ __launch_bounds__(1024) void k_tail(
    const float* __restrict__ z, const float* __restrict__ emb,
    const float* __restrict__ embed_prob,
    const unsigned long long* __restrict__ wscol,
    const unsigned int* __restrict__ counts,
    const double* __restrict__ loss_acc,
    float* __restrict__ out_newemb, float* __restrict__ out_loss,
    float* __restrict__ out_perp, float* __restrict__ out_prob) {
    const int k = blockIdx.x * 16 + (threadIdx.x >> 6);
    const int c = threadIdx.x & 63;

    float avg  = (float)counts[k] * (1.0f / 65536.0f);
    float pnew = __fadd_rn(__fmul_rn(embed_prob[k], 0.99f),
                           __fmul_rn(0.01f, avg));
    float tt = __fdiv_rn(__fmul_rn(__fmul_rn(pnew, 1024.0f), 10.0f), 0.01f);
    float dk = expf(__fsub_rn(-tt, 1e-3f));
    float omd = __fsub_rn(1.0f, dk);

    unsigned long long ck = wscol[k];
    int cn  = (int)(~(unsigned int)(ck & 0xFFFFFFFFull));
    int cb  = cn >> 12;
    int chw = cn & 4095;

    float rf = z[(size_t)cb * 262144 + (size_t)c * 4096 + chw];
    float e  = emb[(size_t)k * 64 + c];
    out_newemb[(size_t)k * 64 + c] =
        __fadd_rn(__fmul_rn(e, omd), __fmul_rn(rf, dk));

    if (blockIdx.x == 0) {
        const int q = threadIdx.x;

        float avg2  = (float)counts[q] * (1.0f / 65536.0f);
        float pnew2 = __fadd_rn(__fmul_rn(embed_prob[q], 0.99f),
                                __fmul_rn(0.01f, avg2));
        out_prob[q] = pnew2;

        float term = __fmul_rn(avg2, logf(__fadd_rn(avg2, 1e-10f)));
        __shared__ double red[1024];
        red[q] = (double)term;
        __syncthreads();
        for (int st = 512; st; st >>= 1) {
            if (q < st) red[q] += red[q + st];
            __syncthreads();
        }
        if (q == 0) {
            float s32 = (float)red[0];
            out_perp[0] = expf(-s32);
            double lm = loss_acc[0] / 4194304.0;
            float  m  = (float)lm;
            out_loss[0] = __fadd_rn(__fmul_rn(0.25f, m), m);  // BETA*m + m
        }
    }
}

extern "C" void kernel_launch(void* const* d_in, const int* in_sizes, int n_in,
                              void* d_out, int out_size, void* d_ws, size_t ws_size,
                              hipStream_t stream) {
    const float* z    = (const float*)d_in[0];   // 16*64*64*64
    const float* emb  = (const float*)d_in[1];   // 1024*64
    const float* prob = (const float*)d_in[2];   // 1024

    float* out        = (float*)d_out;
    float* out_zq     = out;                 // 4194304 floats (16.777 MB)
    float* out_loss   = out + 4194304;
    float* out_perp   = out + 4194305;
    float* out_newemb = out + 4194306;
    float* out_prob   = out + 4259842;
    float* out_idx    = out + 4260866;

    char* ws = (char*)d_ws;
    unsigned long long* wsrow = (unsigned long long*)(ws + WS_ROW);
    unsigned long long* wscol = (unsigned long long*)(ws + WS_COL);
    unsigned int*       cnts  = (unsigned int*)(ws + WS_CNT);
    double*             lacc  = (double*)(ws + WS_LOSS);
    float*              en2   = (float*)(ws + WS_EN2);
    unsigned int*       lcnt  = (unsigned int*)(ws + WS_LCNT);
    float*              zn2   = (float*)(ws + WS_ZN2);
    unsigned short*     ebh   = (unsigned short*)(ws + WS_EBH);
    unsigned short*     ebl   = (unsigned short*)(ws + WS_EBL);
    unsigned int*       list  = (unsigned int*)(ws + WS_LIST);
    float*              cbm   = (float*)(ws + WS_CBM);

    // out_zq doubles as scratch before k_tokens rewrites it:
    //   zbf_hi u16[4.2M] @ bytes [0, 8388608)
    //   zbf_lo u16[4.2M] @ bytes [8388608, 16777216)
    unsigned short* zbh = (unsigned short*)out_zq;
    unsigned short* zbl = (unsigned short*)((char*)out_zq + 8388608);

    hipMemsetAsync(d_ws, 0, WS_ZERO, stream);

    hipLaunchKernelGGL(k_prep, dim3(1028), dim3(256), 0, stream,
                       z, emb, en2, zn2,
                       (unsigned int*)zbh, (unsigned int*)zbl,
                       (unsigned int*)ebh, (unsigned int*)ebl);
    hipLaunchKernelGGL(k_mfma, dim3(512), dim3(512), 0, stream,
                       zbh, zbl, ebh, ebl, zn2, en2, cbm, wsrow, lcnt, list);
    hipLaunchKernelGGL(k_rescore, dim3(2048), dim3(256), 0, stream,
                       z, emb, zn2, en2, cbm, list, lcnt, wscol, wsrow);
    hipLaunchKernelGGL(k_tokens, dim3(256), dim3(256), 0, stream,
                       z, emb, wsrow, cnts, lacc, out_zq, out_idx);
    hipLaunchKernelGGL(k_tail, dim3(64), dim3(1024), 0, stream,
                       z, emb, prob, wscol, cnts, lacc,
                       out_newemb, out_loss, out_perp, out_prob);
}